// Round 5
// baseline (176.704 us; speedup 1.0000x reference)
//
#include <hip/hip_runtime.h>

// SegmentTree scatter-update + path propagation — direct-scatter fused version.
// capacity C = 2^23, n_updates = 2^20, tree = 2C floats (64 MiB).
//
// d_ws layout:
//   [0, C/8)           bitmap  uint[C/32] — 1 dirty bit per leaf (1 MiB)
//   [C/8, C/8+C/2048)  l11flag uchar[4096] — per-block L11 dirty (rewritten)
//
// Pipeline (4 dispatches):
//   1. clear:   zero the 1 MiB bitmap (own kernel — rocclr fill took 41 us).
//   2. scatter: out[C+idx] = val (random 4B store, the irreducible scatter);
//               atomicOr leaf bit into L2-resident bitmap.
//   3. merge:   thread = 8 leaves: read tree leaves + out leaves (float4,
//               dirty lines L2/L3-warm from scatter), select by bitmap byte,
//               rewrite leaves full-line; L1..L3 in registers, L4..L11 via
//               LDS (block = 2048-leaf subtree); clean nodes copied from tree.
//   4. tail:    one block, L12..L23 (4095 nodes) in LDS; out[0] = tree[0].
// Exact same pairwise sums as reference -> absmax 0.

typedef unsigned int uint;
typedef unsigned char uchar;

__global__ void clear_kernel(uint4* __restrict__ bm4, int n4) {
    int i = blockIdx.x * blockDim.x + threadIdx.x;
    if (i < n4) bm4[i] = make_uint4(0u, 0u, 0u, 0u);
}

__global__ void scatter_kernel(const int* __restrict__ idx,
                               const float* __restrict__ val,
                               float* __restrict__ out,
                               uint* __restrict__ bm,
                               int C, int n) {
    int i = blockIdx.x * blockDim.x + threadIdx.x;
    if (i < n) {
        int j = idx[i];
        out[C + j] = val[i];
        atomicOr(&bm[j >> 5], 1u << (j & 31));
    }
}

__global__ __launch_bounds__(256)
void merge_kernel(const float* __restrict__ tree,
                  const uint* __restrict__ bm,
                  uchar* __restrict__ l11flag,
                  float* __restrict__ out, int C) {
    const int t = blockIdx.x * 256 + threadIdx.x;   // 0 .. C/8-1
    const int leaf0 = t * 8;

    // dirty bits for this thread's 8 leaves = byte t of the bitmap
    uint f = ((const uchar*)bm)[t];

    // ---- leaves: tree values + scattered values (in out), select, rewrite ----
    const float4* tl = (const float4*)(tree + C + leaf0);
    float4 ta = tl[0], tb = tl[1];
    const float4* ol = (const float4*)(out + C + leaf0);
    float4 oa = ol[0], ob = ol[1];   // poison where clean — never selected

    float l0 = (f & 0x01u) ? oa.x : ta.x;
    float l1 = (f & 0x02u) ? oa.y : ta.y;
    float l2 = (f & 0x04u) ? oa.z : ta.z;
    float l3 = (f & 0x08u) ? oa.w : ta.w;
    float l4 = (f & 0x10u) ? ob.x : tb.x;
    float l5 = (f & 0x20u) ? ob.y : tb.y;
    float l6 = (f & 0x40u) ? ob.z : tb.z;
    float l7 = (f & 0x80u) ? ob.w : tb.w;

    *(float4*)(out + C + leaf0)     = make_float4(l0, l1, l2, l3);
    *(float4*)(out + C + leaf0 + 4) = make_float4(l4, l5, l6, l7);

    // ---- L1 (4 nodes/thread) ----
    uint d10 = (f & 0x03u) != 0u;
    uint d11 = (f & 0x0Cu) != 0u;
    uint d12 = (f & 0x30u) != 0u;
    uint d13 = (f & 0xC0u) != 0u;
    float4 t1 = *(const float4*)(tree + (C >> 1) + 4 * t);
    float4 v1;
    v1.x = d10 ? l0 + l1 : t1.x;
    v1.y = d11 ? l2 + l3 : t1.y;
    v1.z = d12 ? l4 + l5 : t1.z;
    v1.w = d13 ? l6 + l7 : t1.w;
    *(float4*)(out + (C >> 1) + 4 * t) = v1;

    // ---- L2 (2 nodes/thread) ----
    float2 t2 = *(const float2*)(tree + (C >> 2) + 2 * t);
    uint d20 = d10 | d11, d21 = d12 | d13;
    float2 v2;
    v2.x = d20 ? v1.x + v1.y : t2.x;
    v2.y = d21 ? v1.z + v1.w : t2.y;
    *(float2*)(out + (C >> 2) + 2 * t) = v2;

    // ---- L3 (1 node/thread) ----
    float t3 = tree[(C >> 3) + t];
    uint d3 = d20 | d21;
    float v3 = d3 ? v2.x + v2.y : t3;
    out[(C >> 3) + t] = v3;

    // ---- L4..L11: block-level LDS reduction (block = 2048 leaves) ----
    __shared__ float sv[256];
    __shared__ uint  sd[256];
    float curv = v3;
    uint  curd = d3;
    const int nb = blockIdx.x * 2048;   // first leaf offset of this block
    for (int lvl = 4; lvl <= 11; ++lvl) {
        sv[threadIdx.x] = curv;
        sd[threadIdx.x] = curd;
        __syncthreads();
        const int A = 2048 >> lvl;      // 128,64,...,1 active threads
        float nv = 0.f;
        uint  nd = 0u;
        if (threadIdx.x < A) {
            nd = sd[2 * threadIdx.x] | sd[2 * threadIdx.x + 1];
            int node = (C >> lvl) + (nb >> lvl) + threadIdx.x;
            float tv = tree[node];
            nv = nd ? sv[2 * threadIdx.x] + sv[2 * threadIdx.x + 1] : tv;
            out[node] = nv;
        }
        __syncthreads();
        curv = nv;
        curd = nd;
    }
    if (threadIdx.x == 0) l11flag[blockIdx.x] = (uchar)curd;
}

// One block: L12..L23 (parents 2048 down to 1, 4095 nodes) + out[0] copy.
__global__ __launch_bounds__(1024)
void tail_kernel(const float* __restrict__ tree,
                 const uchar* __restrict__ l11flag,
                 float* __restrict__ out) {
    __shared__ float va[2048];
    __shared__ uint  da[2048];
    const int tid = threadIdx.x;
    for (int i = tid; i < 2048; i += 1024) {
        int p = 2048 + i;
        uint nd = (uint)l11flag[2 * i] | (uint)l11flag[2 * i + 1];
        float v = nd ? out[2 * p] + out[2 * p + 1] : tree[p];
        out[p] = v;
        va[i] = v;
        da[i] = nd;
    }
    __syncthreads();
    for (int M = 1024; M >= 1; M >>= 1) {
        float v = 0.f;
        uint  nd = 0u;
        if (tid < M) {
            int p = M + tid;
            nd = da[2 * tid] | da[2 * tid + 1];
            v = nd ? va[2 * tid] + va[2 * tid + 1] : tree[p];
            out[p] = v;
        }
        __syncthreads();
        if (tid < M) { va[tid] = v; da[tid] = nd; }
        __syncthreads();
    }
    if (tid == 0) out[0] = tree[0];
}

extern "C" void kernel_launch(void* const* d_in, const int* in_sizes, int n_in,
                              void* d_out, int out_size, void* d_ws, size_t ws_size,
                              hipStream_t stream) {
    const float* tree    = (const float*)d_in[0];
    const int*   indices = (const int*)d_in[1];
    const float* values  = (const float*)d_in[2];
    float* out = (float*)d_out;

    const int two_cap = in_sizes[0];     // 16,777,216
    const int C       = two_cap >> 1;    // 8,388,608
    const int n_upd   = in_sizes[1];     // 1,048,576

    uint*  bm  = (uint*)d_ws;                       // C/32 words = 1 MiB
    uchar* l11 = (uchar*)d_ws + (size_t)(C >> 3);   // 4 KiB, fully rewritten

    // 1. Clear the 1 MiB dirty bitmap (own kernel, ~1 us).
    const int nbm4 = C >> 7;             // uint4 count = 65536
    clear_kernel<<<nbm4 / 256, 256, 0, stream>>>((uint4*)d_ws, nbm4);

    // 2. Scatter leaf values directly into out + mark bitmap.
    scatter_kernel<<<(n_upd + 255) / 256, 256, 0, stream>>>(indices, values,
                                                            out, bm, C, n_upd);

    // 3. Fused select + L1..L11 (tree read once, out written once).
    merge_kernel<<<C / 2048, 256, 0, stream>>>(tree, bm, l11, out, C);

    // 4. L12..L23 + out[0].
    tail_kernel<<<1, 1024, 0, stream>>>(tree, l11, out);
}